// Round 1
// baseline (418.340 us; speedup 1.0000x reference)
//
#include <hip/hip_runtime.h>

#define B_ 4
#define S_ 2048
#define D_ 1024
#define H_ 16
#define HD_ 64

typedef __bf16 bf16x8 __attribute__((ext_vector_type(8)));
typedef float f32x4 __attribute__((ext_vector_type(4)));
typedef unsigned short u16;

__device__ __forceinline__ u16 f2b(float f) {
  unsigned u = __builtin_bit_cast(unsigned, f);
  return (u16)((u + 0x7FFFu + ((u >> 16) & 1u)) >> 16);
}

__device__ __forceinline__ void gll16(const void* g, void* l) {
  __builtin_amdgcn_global_load_lds(
      (const __attribute__((address_space(1))) void*)g,
      (__attribute__((address_space(3))) void*)l, 16, 0, 0);
}

__device__ __forceinline__ f32x4 mfma16(bf16x8 a, bf16x8 b, f32x4 c) {
  return __builtin_amdgcn_mfma_f32_16x16x32_bf16(a, b, c, 0, 0, 0);
}

// ---- x: f32 -> bf16, vectorized x4 ----
__global__ __launch_bounds__(256) void k_cvt(const float* __restrict__ in,
                                             u16* __restrict__ out, int n4) {
  int i = blockIdx.x * 256 + threadIdx.x;
  if (i < n4) {
    float4 f = reinterpret_cast<const float4*>(in)[i];
    ushort4 o;
    o.x = f2b(f.x); o.y = f2b(f.y); o.z = f2b(f.z); o.w = f2b(f.w);
    reinterpret_cast<ushort4*>(out)[i] = o;
  }
}

// ---- W[1024][1024] f32 -> Wt[n][k] bf16 (transpose via LDS tile) ----
__global__ __launch_bounds__(256) void k_wt(const float* __restrict__ W,
                                            u16* __restrict__ Wt) {
  __shared__ float tile[32][33];
  int bx = blockIdx.x * 32, by = blockIdx.y * 32;
  int tx = threadIdx.x, ty = threadIdx.y;
  #pragma unroll
  for (int i = ty; i < 32; i += 8)
    tile[i][tx] = W[(size_t)(by + i) * D_ + bx + tx];
  __syncthreads();
  #pragma unroll
  for (int i = ty; i < 32; i += 8)
    Wt[(size_t)(bx + i) * D_ + by + tx] = f2b(tile[tx][i]);
}

// ---- bf16 GEMM: C[m][n] = sum_k A[m][k] * Bt[n][k]   (m97-style 128x128) ----
// MODE 0: N=3072 fused QKV epilogue (scatter to per-head layouts, V transposed)
// MODE 1: N=1024 output projection, f32 + bias
template <int MODE>
__global__ __launch_bounds__(256) void k_gemm(
    const u16* __restrict__ A, const u16* __restrict__ Bt, int N, int K,
    u16* __restrict__ q, u16* __restrict__ kk, u16* __restrict__ v,
    const float* __restrict__ bias, float* __restrict__ out) {
  constexpr int BK = 32;
  __shared__ __align__(16) u16 As[128 * BK];
  __shared__ __align__(16) u16 Bs[128 * BK];
  const int m0 = blockIdx.y * 128, n0 = blockIdx.x * 128;
  const int t = threadIdx.x, lane = t & 63, w = t >> 6;
  const int wr = w >> 1, wc = w & 1;
  const int lr = lane & 15, lg = lane >> 4;
  f32x4 acc[4][4] = {};
  const int rA = t >> 2, cA = (t & 3) * 8;
  const u16* pa0 = A + (size_t)(m0 + rA) * K + cA;
  const u16* pa1 = pa0 + (size_t)64 * K;
  const u16* pb0 = Bt + (size_t)(n0 + rA) * K + cA;
  const u16* pb1 = pb0 + (size_t)64 * K;
  for (int k0 = 0; k0 < K; k0 += BK) {
    gll16(pa0 + k0, As + t * 8);
    gll16(pa1 + k0, As + 64 * BK + t * 8);
    gll16(pb0 + k0, Bs + t * 8);
    gll16(pb1 + k0, Bs + 64 * BK + t * 8);
    __syncthreads();
    bf16x8 af[4], bf[4];
    #pragma unroll
    for (int i = 0; i < 4; ++i)
      af[i] = *reinterpret_cast<const bf16x8*>(
          &As[(wr * 64 + i * 16 + lr) * BK + lg * 8]);
    #pragma unroll
    for (int j = 0; j < 4; ++j)
      bf[j] = *reinterpret_cast<const bf16x8*>(
          &Bs[(wc * 64 + j * 16 + lr) * BK + lg * 8]);
    #pragma unroll
    for (int i = 0; i < 4; ++i)
      #pragma unroll
      for (int j = 0; j < 4; ++j)
        acc[i][j] = mfma16(af[i], bf[j], acc[i][j]);
    __syncthreads();
  }
  #pragma unroll
  for (int i = 0; i < 4; ++i) {
    #pragma unroll
    for (int j = 0; j < 4; ++j) {
      #pragma unroll
      for (int r = 0; r < 4; ++r) {
        int m = m0 + wr * 64 + i * 16 + lg * 4 + r;
        int n = n0 + wc * 64 + j * 16 + lr;
        float val = acc[i][j][r];
        if (MODE == 0) {
          int which = n >> 10, nn = n & 1023;
          int h = nn >> 6, hd = nn & 63;
          int b = m >> 11, s = m & 2047;
          size_t bh = (size_t)(b * H_ + h);
          if (which == 0)
            q[(bh * S_ + s) * HD_ + hd] = f2b(val * 0.125f);  // fold 1/sqrt(64)
          else if (which == 1)
            kk[(bh * S_ + s) * HD_ + hd] = f2b(val);
          else
            v[(bh * HD_ + hd) * S_ + s] = f2b(val);  // V stored transposed
        } else {
          out[(size_t)m * N + n] = val + bias[n];
        }
      }
    }
  }
}

// ---- causal flash attention: 4 waves x 16 q-rows, KV tiles of 64 ----
__global__ __launch_bounds__(256) void k_attn(
    const u16* __restrict__ Qg, const u16* __restrict__ Kg,
    const u16* __restrict__ Vtg, u16* __restrict__ ctx) {
  __shared__ __align__(16) u16 Ks[64 * 64];      // [key][hd]
  __shared__ __align__(16) u16 Vs[64 * 64];      // [hd][key]
  __shared__ __align__(16) u16 Ps[4][16 * 64];   // per-wave P
  const int q0 = blockIdx.x * 64;
  const int bh = blockIdx.y;
  const int t = threadIdx.x, lane = t & 63, w = t >> 6;
  const int lr = lane & 15, lg = lane >> 4;
  const size_t base = (size_t)bh * S_ * HD_;
  bf16x8 qf0 = *reinterpret_cast<const bf16x8*>(
      &Qg[base + (size_t)(q0 + w * 16 + lr) * HD_ + lg * 8]);
  bf16x8 qf1 = *reinterpret_cast<const bf16x8*>(
      &Qg[base + (size_t)(q0 + w * 16 + lr) * HD_ + 32 + lg * 8]);
  float m_r[4], l_r[4];
  f32x4 o_acc[4] = {};
  #pragma unroll
  for (int r = 0; r < 4; ++r) { m_r[r] = -1e30f; l_r[r] = 0.f; }
  const int sr = t >> 3, sc8 = (t & 7) * 8;
  for (int kb = 0; kb <= q0; kb += 64) {
    gll16(Kg + base + (size_t)(kb + sr) * HD_ + sc8, Ks + t * 8);
    gll16(Kg + base + (size_t)(kb + 32 + sr) * HD_ + sc8, Ks + 32 * 64 + t * 8);
    gll16(Vtg + base + (size_t)sr * S_ + kb + sc8, Vs + t * 8);
    gll16(Vtg + base + (size_t)(32 + sr) * S_ + kb + sc8, Vs + 32 * 64 + t * 8);
    __syncthreads();
    f32x4 sc[4];
    #pragma unroll
    for (int nt = 0; nt < 4; ++nt) {
      bf16x8 kf0 = *reinterpret_cast<const bf16x8*>(
          &Ks[(nt * 16 + lr) * 64 + lg * 8]);
      bf16x8 kf1 = *reinterpret_cast<const bf16x8*>(
          &Ks[(nt * 16 + lr) * 64 + 32 + lg * 8]);
      f32x4 a = {};
      a = mfma16(qf0, kf0, a);
      a = mfma16(qf1, kf1, a);
      sc[nt] = a;
    }
    if (kb == q0) {  // diagonal block: causal mask
      #pragma unroll
      for (int nt = 0; nt < 4; ++nt) {
        int col = nt * 16 + lr;
        #pragma unroll
        for (int r = 0; r < 4; ++r)
          if (col > w * 16 + lg * 4 + r) sc[nt][r] = -1e30f;
      }
    }
    float tmax[4], scal[4], rs[4];
    #pragma unroll
    for (int r = 0; r < 4; ++r)
      tmax[r] = fmaxf(fmaxf(sc[0][r], sc[1][r]), fmaxf(sc[2][r], sc[3][r]));
    #pragma unroll
    for (int msk = 1; msk < 16; msk <<= 1)
      #pragma unroll
      for (int r = 0; r < 4; ++r)
        tmax[r] = fmaxf(tmax[r], __shfl_xor(tmax[r], msk));
    float p[4][4];
    #pragma unroll
    for (int r = 0; r < 4; ++r) {
      float mn = fmaxf(m_r[r], tmax[r]);
      scal[r] = __expf(m_r[r] - mn);
      m_r[r] = mn;
      float s = 0.f;
      #pragma unroll
      for (int nt = 0; nt < 4; ++nt) {
        p[nt][r] = __expf(sc[nt][r] - mn);
        s += p[nt][r];
      }
      rs[r] = s;
    }
    #pragma unroll
    for (int msk = 1; msk < 16; msk <<= 1)
      #pragma unroll
      for (int r = 0; r < 4; ++r)
        rs[r] += __shfl_xor(rs[r], msk);
    #pragma unroll
    for (int r = 0; r < 4; ++r) {
      l_r[r] = l_r[r] * scal[r] + rs[r];
      #pragma unroll
      for (int ht = 0; ht < 4; ++ht) o_acc[ht][r] *= scal[r];
    }
    #pragma unroll
    for (int nt = 0; nt < 4; ++nt)
      #pragma unroll
      for (int r = 0; r < 4; ++r)
        Ps[w][(lg * 4 + r) * 64 + nt * 16 + lr] = f2b(p[nt][r]);
    bf16x8 pf0 = *reinterpret_cast<const bf16x8*>(&Ps[w][lr * 64 + lg * 8]);
    bf16x8 pf1 = *reinterpret_cast<const bf16x8*>(&Ps[w][lr * 64 + 32 + lg * 8]);
    #pragma unroll
    for (int ht = 0; ht < 4; ++ht) {
      bf16x8 vf0 = *reinterpret_cast<const bf16x8*>(
          &Vs[(ht * 16 + lr) * 64 + lg * 8]);
      bf16x8 vf1 = *reinterpret_cast<const bf16x8*>(
          &Vs[(ht * 16 + lr) * 64 + 32 + lg * 8]);
      o_acc[ht] = mfma16(pf0, vf0, o_acc[ht]);
      o_acc[ht] = mfma16(pf1, vf1, o_acc[ht]);
    }
    __syncthreads();
  }
  const int b = bh >> 4, h = bh & 15;
  #pragma unroll
  for (int ht = 0; ht < 4; ++ht) {
    #pragma unroll
    for (int r = 0; r < 4; ++r) {
      int row = q0 + w * 16 + lg * 4 + r;
      int col = h * 64 + ht * 16 + lr;
      ctx[((size_t)b * S_ + row) * D_ + col] = f2b(o_acc[ht][r] / l_r[r]);
    }
  }
}

extern "C" void kernel_launch(void* const* d_in, const int* in_sizes, int n_in,
                              void* d_out, int out_size, void* d_ws, size_t ws_size,
                              hipStream_t stream) {
  const float* x  = (const float*)d_in[0];
  const float* Wq = (const float*)d_in[1];
  const float* Wk = (const float*)d_in[2];
  const float* Wv = (const float*)d_in[3];
  const float* Wo = (const float*)d_in[4];
  const float* bo = (const float*)d_in[5];
  float* out = (float*)d_out;
  (void)in_sizes; (void)n_in; (void)out_size; (void)ws_size;

  char* p = (char*)d_ws;
  const size_t NTOK = (size_t)B_ * S_;  // 8192
  u16* xb    = (u16*)p; p += NTOK * D_ * 2;           // 16 MiB
  u16* wqkvt = (u16*)p; p += (size_t)3 * D_ * D_ * 2; // 6 MiB  [3072][1024]
  u16* wot   = (u16*)p; p += (size_t)D_ * D_ * 2;     // 2 MiB
  u16* Qg    = (u16*)p; p += NTOK * D_ * 2;           // [bh][s][hd]
  u16* Kg    = (u16*)p; p += NTOK * D_ * 2;           // [bh][s][hd]
  u16* Vtg   = (u16*)p; p += NTOK * D_ * 2;           // [bh][hd][s]
  u16* ctx   = (u16*)p; p += NTOK * D_ * 2;           // [b][s][d]

  int n4 = (int)(NTOK * D_ / 4);
  k_cvt<<<dim3((n4 + 255) / 256), dim3(256), 0, stream>>>(x, xb, n4);
  dim3 tb(32, 8), tg(32, 32);
  k_wt<<<tg, tb, 0, stream>>>(Wq, wqkvt);
  k_wt<<<tg, tb, 0, stream>>>(Wk, wqkvt + (size_t)D_ * D_);
  k_wt<<<tg, tb, 0, stream>>>(Wv, wqkvt + (size_t)2 * D_ * D_);
  k_wt<<<tg, tb, 0, stream>>>(Wo, wot);
  k_gemm<0><<<dim3(3 * D_ / 128, NTOK / 128), dim3(256), 0, stream>>>(
      xb, wqkvt, 3 * D_, D_, Qg, Kg, Vtg, nullptr, nullptr);
  k_attn<<<dim3(S_ / 64, B_ * H_), dim3(256), 0, stream>>>(Qg, Kg, Vtg, ctx);
  k_gemm<1><<<dim3(D_ / 128, NTOK / 128), dim3(256), 0, stream>>>(
      ctx, wot, D_, D_, nullptr, nullptr, nullptr, bo, out);
}

// Round 2
// 264.121 us; speedup vs baseline: 1.5839x; 1.5839x over previous
//
#include <hip/hip_runtime.h>

#define B_ 4
#define S_ 2048
#define D_ 1024
#define H_ 16
#define HD_ 64

typedef __bf16 bf16x8 __attribute__((ext_vector_type(8)));
typedef float f32x4 __attribute__((ext_vector_type(4)));
typedef unsigned short u16;

__device__ __forceinline__ u16 f2b(float f) {
  unsigned u = __builtin_bit_cast(unsigned, f);
  return (u16)((u + 0x7FFFu + ((u >> 16) & 1u)) >> 16);
}

__device__ __forceinline__ void gll16(const void* g, void* l) {
  __builtin_amdgcn_global_load_lds(
      (const __attribute__((address_space(1))) void*)g,
      (__attribute__((address_space(3))) void*)l, 16, 0, 0);
}

__device__ __forceinline__ f32x4 mfma16(bf16x8 a, bf16x8 b, f32x4 c) {
  return __builtin_amdgcn_mfma_f32_16x16x32_bf16(a, b, c, 0, 0, 0);
}

// ---- x: f32 -> bf16, vectorized x4 ----
__global__ __launch_bounds__(256) void k_cvt(const float* __restrict__ in,
                                             u16* __restrict__ out, int n4) {
  int i = blockIdx.x * 256 + threadIdx.x;
  if (i < n4) {
    float4 f = reinterpret_cast<const float4*>(in)[i];
    ushort4 o;
    o.x = f2b(f.x); o.y = f2b(f.y); o.z = f2b(f.z); o.w = f2b(f.w);
    reinterpret_cast<ushort4*>(out)[i] = o;
  }
}

// ---- W[1024][1024] f32 -> Wt[n][k] bf16 (transpose via LDS tile) ----
__global__ __launch_bounds__(256) void k_wt(const float* __restrict__ W,
                                            u16* __restrict__ Wt) {
  __shared__ float tile[32][33];
  int bx = blockIdx.x * 32, by = blockIdx.y * 32;
  int tx = threadIdx.x, ty = threadIdx.y;
  #pragma unroll
  for (int i = ty; i < 32; i += 8)
    tile[i][tx] = W[(size_t)(by + i) * D_ + bx + tx];
  __syncthreads();
  #pragma unroll
  for (int i = ty; i < 32; i += 8)
    Wt[(size_t)(bx + i) * D_ + by + tx] = f2b(tile[tx][i]);
}

// ---- bf16 GEMM: C[m][n] = sum_k A[m][k] * Bt[n][k]   (m97-style 128x128) ----
template <int MODE>
__global__ __launch_bounds__(256) void k_gemm(
    const u16* __restrict__ A, const u16* __restrict__ Bt, int N, int K,
    u16* __restrict__ q, u16* __restrict__ kk, u16* __restrict__ v,
    const float* __restrict__ bias, float* __restrict__ out) {
  constexpr int BK = 32;
  __shared__ __align__(16) u16 As[128 * BK];
  __shared__ __align__(16) u16 Bs[128 * BK];
  const int m0 = blockIdx.y * 128, n0 = blockIdx.x * 128;
  const int t = threadIdx.x, lane = t & 63, w = t >> 6;
  const int wr = w >> 1, wc = w & 1;
  const int lr = lane & 15, lg = lane >> 4;
  f32x4 acc[4][4] = {};
  const int rA = t >> 2, cA = (t & 3) * 8;
  const u16* pa0 = A + (size_t)(m0 + rA) * K + cA;
  const u16* pa1 = pa0 + (size_t)64 * K;
  const u16* pb0 = Bt + (size_t)(n0 + rA) * K + cA;
  const u16* pb1 = pb0 + (size_t)64 * K;
  for (int k0 = 0; k0 < K; k0 += BK) {
    gll16(pa0 + k0, As + t * 8);
    gll16(pa1 + k0, As + 64 * BK + t * 8);
    gll16(pb0 + k0, Bs + t * 8);
    gll16(pb1 + k0, Bs + 64 * BK + t * 8);
    __syncthreads();
    bf16x8 af[4], bf[4];
    #pragma unroll
    for (int i = 0; i < 4; ++i)
      af[i] = *reinterpret_cast<const bf16x8*>(
          &As[(wr * 64 + i * 16 + lr) * BK + lg * 8]);
    #pragma unroll
    for (int j = 0; j < 4; ++j)
      bf[j] = *reinterpret_cast<const bf16x8*>(
          &Bs[(wc * 64 + j * 16 + lr) * BK + lg * 8]);
    #pragma unroll
    for (int i = 0; i < 4; ++i)
      #pragma unroll
      for (int j = 0; j < 4; ++j)
        acc[i][j] = mfma16(af[i], bf[j], acc[i][j]);
    __syncthreads();
  }
  #pragma unroll
  for (int i = 0; i < 4; ++i) {
    #pragma unroll
    for (int j = 0; j < 4; ++j) {
      #pragma unroll
      for (int r = 0; r < 4; ++r) {
        int m = m0 + wr * 64 + i * 16 + lg * 4 + r;
        int n = n0 + wc * 64 + j * 16 + lr;
        float val = acc[i][j][r];
        if (MODE == 0) {
          int which = n >> 10, nn = n & 1023;
          int h = nn >> 6, hd = nn & 63;
          int b = m >> 11, s = m & 2047;
          size_t bh = (size_t)(b * H_ + h);
          if (which == 0)
            q[(bh * S_ + s) * HD_ + hd] = f2b(val * 0.125f);  // fold 1/sqrt(64)
          else if (which == 1)
            kk[(bh * S_ + s) * HD_ + hd] = f2b(val);
          else
            v[(bh * HD_ + hd) * S_ + s] = f2b(val);  // V stored transposed
        } else {
          out[(size_t)m * N + n] = val + bias[n];
        }
      }
    }
  }
}

// ---- causal flash attention v2 ----
// grid (16, B*H). wg jx handles q-tiles {jx, 31-jx} (triangle pairing).
// KV tiles of 64 double-buffered in LDS; K/V swizzled via pre-swizzled
// global source (gll_lds dest must stay lane-linear); Ps swizzled both sides.
__global__ __launch_bounds__(256, 4) void k_attn(
    const u16* __restrict__ Qg, const u16* __restrict__ Kg,
    const u16* __restrict__ Vtg, u16* __restrict__ ctx) {
  __shared__ __align__(16) u16 Ks[2][64 * 64];   // [key][hd], chunk-swizzled
  __shared__ __align__(16) u16 Vs[2][64 * 64];   // [hd][key], chunk-swizzled
  __shared__ __align__(16) u16 Ps[4][16 * 64];   // per-wave P, swizzled
  const int jx = blockIdx.x;
  const int bh = blockIdx.y;
  const int qa = jx, qb = 31 - jx;
  const int t = threadIdx.x, lane = t & 63, w = t >> 6;
  const int lr = lane & 15, lg = lane >> 4;
  const size_t base = (size_t)bh * S_ * HD_;
  // staging coords: LDS dest is linear t*16B -> (row = t>>3, dest chunk = t&7);
  // source chunk = destchunk ^ (row&7) gives swizzled storage.
  const int srow = t >> 3;
  const int sch = (t & 7) ^ (srow & 7);

  // Q fragments for both tiles (scale folded into Q upstream)
  bf16x8 qfA0, qfA1, qfB0, qfB1;
  {
    const u16* qp = Qg + base + (size_t)(qa * 64 + w * 16 + lr) * HD_;
    qfA0 = *reinterpret_cast<const bf16x8*>(qp + lg * 8);
    qfA1 = *reinterpret_cast<const bf16x8*>(qp + 32 + lg * 8);
    qp = Qg + base + (size_t)(qb * 64 + w * 16 + lr) * HD_;
    qfB0 = *reinterpret_cast<const bf16x8*>(qp + lg * 8);
    qfB1 = *reinterpret_cast<const bf16x8*>(qp + 32 + lg * 8);
  }
  float mA[4], lA[4], mB[4], lB[4];
  f32x4 oA[4] = {}, oB[4] = {};
  #pragma unroll
  for (int r = 0; r < 4; ++r) { mA[r] = -1e30f; lA[r] = 0.f; mB[r] = -1e30f; lB[r] = 0.f; }

  const int sx = lr & 7;  // read-side swizzle XOR (row&7 with row = nt*16+lr)

  auto stage = [&](int buf, int kb) {
    gll16(Kg + base + (size_t)(kb + srow) * HD_ + sch * 8, &Ks[buf][t * 8]);
    gll16(Kg + base + (size_t)(kb + 32 + srow) * HD_ + sch * 8, &Ks[buf][2048 + t * 8]);
    gll16(Vtg + base + (size_t)srow * S_ + kb + sch * 8, &Vs[buf][t * 8]);
    gll16(Vtg + base + (size_t)(32 + srow) * S_ + kb + sch * 8, &Vs[buf][2048 + t * 8]);
  };

  auto attend = [&](int buf, bf16x8 qf0, bf16x8 qf1, float* m_r, float* l_r,
                    f32x4* o_acc, bool diag) {
    f32x4 sc[4];
    #pragma unroll
    for (int nt = 0; nt < 4; ++nt) {
      const u16* kp = &Ks[buf][(nt * 16 + lr) * 64];
      bf16x8 kf0 = *reinterpret_cast<const bf16x8*>(kp + ((lg ^ sx) * 8));
      bf16x8 kf1 = *reinterpret_cast<const bf16x8*>(kp + (((lg + 4) ^ sx) * 8));
      f32x4 a = {};
      a = mfma16(qf0, kf0, a);
      a = mfma16(qf1, kf1, a);
      sc[nt] = a;
    }
    if (diag) {
      #pragma unroll
      for (int nt = 0; nt < 4; ++nt) {
        int col = nt * 16 + lr;
        #pragma unroll
        for (int r = 0; r < 4; ++r)
          if (col > w * 16 + lg * 4 + r) sc[nt][r] = -1e30f;
      }
    }
    float tmax[4], scal[4], rs[4];
    #pragma unroll
    for (int r = 0; r < 4; ++r)
      tmax[r] = fmaxf(fmaxf(sc[0][r], sc[1][r]), fmaxf(sc[2][r], sc[3][r]));
    #pragma unroll
    for (int msk = 1; msk < 16; msk <<= 1)
      #pragma unroll
      for (int r = 0; r < 4; ++r)
        tmax[r] = fmaxf(tmax[r], __shfl_xor(tmax[r], msk));
    float p[4][4];
    #pragma unroll
    for (int r = 0; r < 4; ++r) {
      float mn = fmaxf(m_r[r], tmax[r]);
      scal[r] = __expf(m_r[r] - mn);
      m_r[r] = mn;
      float s = 0.f;
      #pragma unroll
      for (int nt = 0; nt < 4; ++nt) {
        p[nt][r] = __expf(sc[nt][r] - mn);
        s += p[nt][r];
      }
      rs[r] = s;
    }
    #pragma unroll
    for (int msk = 1; msk < 16; msk <<= 1)
      #pragma unroll
      for (int r = 0; r < 4; ++r)
        rs[r] += __shfl_xor(rs[r], msk);
    #pragma unroll
    for (int r = 0; r < 4; ++r) {
      l_r[r] = l_r[r] * scal[r] + rs[r];
      #pragma unroll
      for (int ht = 0; ht < 4; ++ht) o_acc[ht][r] *= scal[r];
    }
    // Ps write, swizzled: elem (row,col) at row*64 + ((col>>3 ^ row&7)<<3) + (col&7)
    #pragma unroll
    for (int nt = 0; nt < 4; ++nt)
      #pragma unroll
      for (int r = 0; r < 4; ++r) {
        int row = lg * 4 + r, col = nt * 16 + lr;
        Ps[w][row * 64 + ((((col >> 3) ^ (row & 7)) << 3) | (col & 7))] =
            f2b(p[nt][r]);
      }
    bf16x8 pf0 = *reinterpret_cast<const bf16x8*>(
        &Ps[w][lr * 64 + ((lg ^ sx) * 8)]);
    bf16x8 pf1 = *reinterpret_cast<const bf16x8*>(
        &Ps[w][lr * 64 + (((lg + 4) ^ sx) * 8)]);
    #pragma unroll
    for (int ht = 0; ht < 4; ++ht) {
      const u16* vp = &Vs[buf][(ht * 16 + lr) * 64];
      bf16x8 vf0 = *reinterpret_cast<const bf16x8*>(vp + ((lg ^ sx) * 8));
      bf16x8 vf1 = *reinterpret_cast<const bf16x8*>(vp + (((lg + 4) ^ sx) * 8));
      o_acc[ht] = mfma16(pf0, vf0, o_acc[ht]);
      o_acc[ht] = mfma16(pf1, vf1, o_acc[ht]);
    }
  };

  stage(0, 0);
  __syncthreads();
  int cur = 0;
  for (int kt = 0; kt <= qb; ++kt) {
    if (kt < qb) stage(cur ^ 1, (kt + 1) * 64);
    if (kt <= qa) attend(cur, qfA0, qfA1, mA, lA, oA, kt == qa);
    attend(cur, qfB0, qfB1, mB, lB, oB, kt == qb);
    __syncthreads();
    cur ^= 1;
  }

  const int b = bh >> 4, h = bh & 15;
  #pragma unroll
  for (int ht = 0; ht < 4; ++ht) {
    #pragma unroll
    for (int r = 0; r < 4; ++r) {
      int rowa = qa * 64 + w * 16 + lg * 4 + r;
      int rowb = qb * 64 + w * 16 + lg * 4 + r;
      int col = h * 64 + ht * 16 + lr;
      ctx[((size_t)b * S_ + rowa) * D_ + col] = f2b(oA[ht][r] / lA[r]);
      ctx[((size_t)b * S_ + rowb) * D_ + col] = f2b(oB[ht][r] / lB[r]);
    }
  }
}

extern "C" void kernel_launch(void* const* d_in, const int* in_sizes, int n_in,
                              void* d_out, int out_size, void* d_ws, size_t ws_size,
                              hipStream_t stream) {
  const float* x  = (const float*)d_in[0];
  const float* Wq = (const float*)d_in[1];
  const float* Wk = (const float*)d_in[2];
  const float* Wv = (const float*)d_in[3];
  const float* Wo = (const float*)d_in[4];
  const float* bo = (const float*)d_in[5];
  float* out = (float*)d_out;
  (void)in_sizes; (void)n_in; (void)out_size; (void)ws_size;

  char* p = (char*)d_ws;
  const size_t NTOK = (size_t)B_ * S_;  // 8192
  u16* xb    = (u16*)p; p += NTOK * D_ * 2;
  u16* wqkvt = (u16*)p; p += (size_t)3 * D_ * D_ * 2;
  u16* wot   = (u16*)p; p += (size_t)D_ * D_ * 2;
  u16* Qg    = (u16*)p; p += NTOK * D_ * 2;           // [bh][s][hd]
  u16* Kg    = (u16*)p; p += NTOK * D_ * 2;           // [bh][s][hd]
  u16* Vtg   = (u16*)p; p += NTOK * D_ * 2;           // [bh][hd][s]
  u16* ctx   = (u16*)p; p += NTOK * D_ * 2;           // [b][s][d]

  int n4 = (int)(NTOK * D_ / 4);
  k_cvt<<<dim3((n4 + 255) / 256), dim3(256), 0, stream>>>(x, xb, n4);
  dim3 tb(32, 8), tg(32, 32);
  k_wt<<<tg, tb, 0, stream>>>(Wq, wqkvt);
  k_wt<<<tg, tb, 0, stream>>>(Wk, wqkvt + (size_t)D_ * D_);
  k_wt<<<tg, tb, 0, stream>>>(Wv, wqkvt + (size_t)2 * D_ * D_);
  k_wt<<<tg, tb, 0, stream>>>(Wo, wot);
  k_gemm<0><<<dim3(3 * D_ / 128, NTOK / 128), dim3(256), 0, stream>>>(
      xb, wqkvt, 3 * D_, D_, Qg, Kg, Vtg, nullptr, nullptr);
  k_attn<<<dim3(16, B_ * H_), dim3(256), 0, stream>>>(Qg, Kg, Vtg, ctx);
  k_gemm<1><<<dim3(D_ / 128, NTOK / 128), dim3(256), 0, stream>>>(
      ctx, wot, D_, D_, nullptr, nullptr, nullptr, bo, out);
}

// Round 3
// 215.989 us; speedup vs baseline: 1.9369x; 1.2228x over previous
//
#include <hip/hip_runtime.h>

#define B_ 4
#define S_ 2048
#define D_ 1024
#define H_ 16
#define HD_ 64

typedef __bf16 bf16x8 __attribute__((ext_vector_type(8)));
typedef float f32x4 __attribute__((ext_vector_type(4)));
typedef float f32x16 __attribute__((ext_vector_type(16)));
typedef unsigned short u16;

__device__ __forceinline__ u16 f2b(float f) {
  unsigned u = __builtin_bit_cast(unsigned, f);
  return (u16)((u + 0x7FFFu + ((u >> 16) & 1u)) >> 16);
}

__device__ __forceinline__ void gll16(const void* g, void* l) {
  __builtin_amdgcn_global_load_lds(
      (const __attribute__((address_space(1))) void*)g,
      (__attribute__((address_space(3))) void*)l, 16, 0, 0);
}

__device__ __forceinline__ f32x4 mfma16(bf16x8 a, bf16x8 b, f32x4 c) {
  return __builtin_amdgcn_mfma_f32_16x16x32_bf16(a, b, c, 0, 0, 0);
}
__device__ __forceinline__ f32x16 mfma32(bf16x8 a, bf16x8 b, f32x16 c) {
  return __builtin_amdgcn_mfma_f32_32x32x16_bf16(a, b, c, 0, 0, 0);
}

__device__ __forceinline__ unsigned cvtpk(float lo, float hi) {
  unsigned r;
  asm("v_cvt_pk_bf16_f32 %0, %1, %2" : "=v"(r) : "v"(lo), "v"(hi));
  return r;
}
// after swap: a = [a_lo, b_lo], b = [a_hi, b_hi]
__device__ __forceinline__ void plswap(unsigned& a, unsigned& b) {
  asm("v_permlane32_swap_b32 %0, %1" : "+v"(a), "+v"(b));
}
__device__ __forceinline__ bf16x8 mk8(unsigned a, unsigned b, unsigned c, unsigned d) {
  union { unsigned u[4]; bf16x8 v; } x;
  x.u[0] = a; x.u[1] = b; x.u[2] = c; x.u[3] = d;
  return x.v;
}

// ---- x: f32 -> bf16, vectorized x4 ----
__global__ __launch_bounds__(256) void k_cvt(const float* __restrict__ in,
                                             u16* __restrict__ out, int n4) {
  int i = blockIdx.x * 256 + threadIdx.x;
  if (i < n4) {
    float4 f = reinterpret_cast<const float4*>(in)[i];
    ushort4 o;
    o.x = f2b(f.x); o.y = f2b(f.y); o.z = f2b(f.z); o.w = f2b(f.w);
    reinterpret_cast<ushort4*>(out)[i] = o;
  }
}

// ---- W[1024][1024] f32 -> Wt[n][k] bf16 (transpose via LDS tile) ----
__global__ __launch_bounds__(256) void k_wt(const float* __restrict__ W,
                                            u16* __restrict__ Wt) {
  __shared__ float tile[32][33];
  int bx = blockIdx.x * 32, by = blockIdx.y * 32;
  int tx = threadIdx.x, ty = threadIdx.y;
  #pragma unroll
  for (int i = ty; i < 32; i += 8)
    tile[i][tx] = W[(size_t)(by + i) * D_ + bx + tx];
  __syncthreads();
  #pragma unroll
  for (int i = ty; i < 32; i += 8)
    Wt[(size_t)(bx + i) * D_ + by + tx] = f2b(tile[tx][i]);
}

// ---- bf16 GEMM: C[m][n] = sum_k A[m][k] * Bt[n][k]   (m97-style 128x128) ----
template <int MODE>
__global__ __launch_bounds__(256) void k_gemm(
    const u16* __restrict__ A, const u16* __restrict__ Bt, int N, int K,
    u16* __restrict__ q, u16* __restrict__ kk, u16* __restrict__ v,
    const float* __restrict__ bias, float* __restrict__ out) {
  constexpr int BK = 32;
  __shared__ __align__(16) u16 As[128 * BK];
  __shared__ __align__(16) u16 Bs[128 * BK];
  const int m0 = blockIdx.y * 128, n0 = blockIdx.x * 128;
  const int t = threadIdx.x, lane = t & 63, w = t >> 6;
  const int wr = w >> 1, wc = w & 1;
  const int lr = lane & 15, lg = lane >> 4;
  f32x4 acc[4][4] = {};
  const int rA = t >> 2, cA = (t & 3) * 8;
  const u16* pa0 = A + (size_t)(m0 + rA) * K + cA;
  const u16* pa1 = pa0 + (size_t)64 * K;
  const u16* pb0 = Bt + (size_t)(n0 + rA) * K + cA;
  const u16* pb1 = pb0 + (size_t)64 * K;
  for (int k0 = 0; k0 < K; k0 += BK) {
    gll16(pa0 + k0, As + t * 8);
    gll16(pa1 + k0, As + 64 * BK + t * 8);
    gll16(pb0 + k0, Bs + t * 8);
    gll16(pb1 + k0, Bs + 64 * BK + t * 8);
    __syncthreads();
    bf16x8 af[4], bf[4];
    #pragma unroll
    for (int i = 0; i < 4; ++i)
      af[i] = *reinterpret_cast<const bf16x8*>(
          &As[(wr * 64 + i * 16 + lr) * BK + lg * 8]);
    #pragma unroll
    for (int j = 0; j < 4; ++j)
      bf[j] = *reinterpret_cast<const bf16x8*>(
          &Bs[(wc * 64 + j * 16 + lr) * BK + lg * 8]);
    #pragma unroll
    for (int i = 0; i < 4; ++i)
      #pragma unroll
      for (int j = 0; j < 4; ++j)
        acc[i][j] = mfma16(af[i], bf[j], acc[i][j]);
    __syncthreads();
  }
  #pragma unroll
  for (int i = 0; i < 4; ++i) {
    #pragma unroll
    for (int j = 0; j < 4; ++j) {
      #pragma unroll
      for (int r = 0; r < 4; ++r) {
        int m = m0 + wr * 64 + i * 16 + lg * 4 + r;
        int n = n0 + wc * 64 + j * 16 + lr;
        float val = acc[i][j][r];
        if (MODE == 0) {
          int which = n >> 10, nn = n & 1023;
          int h = nn >> 6, hd = nn & 63;
          int b = m >> 11, s = m & 2047;
          size_t bh = (size_t)(b * H_ + h);
          if (which == 0)
            q[(bh * S_ + s) * HD_ + hd] = f2b(val * 0.1803368801111f);  // 1/8 * log2(e)
          else if (which == 1)
            kk[(bh * S_ + s) * HD_ + hd] = f2b(val);
          else
            v[(bh * HD_ + hd) * S_ + s] = f2b(val);  // V stored transposed
        } else {
          out[(size_t)m * N + n] = val + bias[n];
        }
      }
    }
  }
}

// ---- causal flash attention v3: swapped QK^T, 32x32 MFMA, in-reg softmax ----
// grid (8, B*H). wg x handles q-tiles {x, 15-x} of 128 rows; 4 waves x 32 q-rows.
// P stays in registers (q = lane&31 lane-local); P->bf16 via cvt_pk+permlane32_swap;
// PV as mfma(V^T, P) -> O^T keeps q lane-local for m/l/rescale.
__global__ __launch_bounds__(256, 2) void k_attn(
    const u16* __restrict__ Qg, const u16* __restrict__ Kg,
    const u16* __restrict__ Vtg, u16* __restrict__ ctx) {
  __shared__ __align__(16) u16 Ks[2][64 * 64];   // [key][hd], chunk-swizzled
  __shared__ __align__(16) u16 Vs[2][64 * 64];   // [hd][key], chunk-swizzled
  const int ja = blockIdx.x, jb = 15 - ja, bh = blockIdx.y;
  const int t = threadIdx.x, l = t & 63, wq = t >> 6;
  const int lo5 = l & 31, hi = l >> 5, sw = l & 7;
  const size_t base = (size_t)bh * S_ * HD_;
  const int srow = t >> 3, sch = (t & 7) ^ (srow & 7);

  const int qw0A = ja * 128 + wq * 32, qw0B = jb * 128 + wq * 32;
  const int dktA = qw0A >> 6, dktB = qw0B >> 6;

  bf16x8 qA[4], qB[4];
  {
    const u16* qp = Qg + base + (size_t)(qw0A + lo5) * HD_ + hi * 8;
    #pragma unroll
    for (int di = 0; di < 4; ++di) qA[di] = *(const bf16x8*)(qp + di * 16);
    qp = Qg + base + (size_t)(qw0B + lo5) * HD_ + hi * 8;
    #pragma unroll
    for (int di = 0; di < 4; ++di) qB[di] = *(const bf16x8*)(qp + di * 16);
  }
  float mA = -1e30f, lsA = 0.f, mB = -1e30f, lsB = 0.f;
  f32x16 oA0 = {}, oA1 = {}, oB0 = {}, oB1 = {};

  auto stage = [&](int buf, int kb) {
    gll16(Kg + base + (size_t)(kb + srow) * HD_ + sch * 8, &Ks[buf][t * 8]);
    gll16(Kg + base + (size_t)(kb + 32 + srow) * HD_ + sch * 8, &Ks[buf][2048 + t * 8]);
    gll16(Vtg + base + (size_t)srow * S_ + kb + sch * 8, &Vs[buf][t * 8]);
    gll16(Vtg + base + (size_t)(32 + srow) * S_ + kb + sch * 8, &Vs[buf][2048 + t * 8]);
  };

  auto attend = [&](int buf, int kt, int qw0, int dkt, const bf16x8 (&qf)[4],
                    float& m_r, float& l_r, f32x16& o0, f32x16& o1) {
    const u16* KB = &Ks[buf][0];
    const u16* VB = &Vs[buf][0];
    // QK^T swapped: D[k][q], k rows = crow(r,hi), q col = lane&31
    f32x16 s0 = {}, s1 = {};
    #pragma unroll
    for (int di = 0; di < 4; ++di)
      s0 = mfma32(*(const bf16x8*)&KB[lo5 * 64 + (((di * 2 + hi) ^ sw) * 8)],
                  qf[di], s0);
    #pragma unroll
    for (int di = 0; di < 4; ++di)
      s1 = mfma32(*(const bf16x8*)&KB[(32 + lo5) * 64 + (((di * 2 + hi) ^ sw) * 8)],
                  qf[di], s1);
    if (kt == dkt) {  // causal mask on diagonal tile, crow space
      int qrel = qw0 + lo5 - kt * 64;
      #pragma unroll
      for (int r = 0; r < 16; ++r) {
        int k0 = (r & 3) + 8 * (r >> 2) + 4 * hi;
        if (k0 > qrel) s0[r] = -1e30f;
        if (k0 + 32 > qrel) s1[r] = -1e30f;
      }
    }
    float tm = fmaxf(s0[0], s1[0]);
    #pragma unroll
    for (int r = 1; r < 16; ++r) tm = fmaxf(tm, fmaxf(s0[r], s1[r]));
    tm = fmaxf(tm, __shfl_xor(tm, 32));
    float mn = fmaxf(m_r, tm);
    float rescale = __builtin_amdgcn_exp2f(m_r - mn);
    m_r = mn;
    float sum = 0.f;
    #pragma unroll
    for (int r = 0; r < 16; ++r) { s0[r] = __builtin_amdgcn_exp2f(s0[r] - mn); sum += s0[r]; }
    #pragma unroll
    for (int r = 0; r < 16; ++r) { s1[r] = __builtin_amdgcn_exp2f(s1[r] - mn); sum += s1[r]; }
    sum += __shfl_xor(sum, 32);
    l_r = l_r * rescale + sum;
    o0 *= rescale;
    o1 *= rescale;
    // pack P -> B-operand fragments (q = lane&31, k = ks*16 + hi*8 + 0..7)
    unsigned a0 = cvtpk(s0[0], s0[1]), b0 = cvtpk(s0[4], s0[5]); plswap(a0, b0);
    unsigned a1 = cvtpk(s0[2], s0[3]), b1 = cvtpk(s0[6], s0[7]); plswap(a1, b1);
    unsigned a2 = cvtpk(s0[8], s0[9]), b2 = cvtpk(s0[12], s0[13]); plswap(a2, b2);
    unsigned a3 = cvtpk(s0[10], s0[11]), b3 = cvtpk(s0[14], s0[15]); plswap(a3, b3);
    bf16x8 p0 = mk8(a0, a1, b0, b1), p1 = mk8(a2, a3, b2, b3);
    a0 = cvtpk(s1[0], s1[1]); b0 = cvtpk(s1[4], s1[5]); plswap(a0, b0);
    a1 = cvtpk(s1[2], s1[3]); b1 = cvtpk(s1[6], s1[7]); plswap(a1, b1);
    a2 = cvtpk(s1[8], s1[9]); b2 = cvtpk(s1[12], s1[13]); plswap(a2, b2);
    a3 = cvtpk(s1[10], s1[11]); b3 = cvtpk(s1[14], s1[15]); plswap(a3, b3);
    bf16x8 p2 = mk8(a0, a1, b0, b1), p3 = mk8(a2, a3, b2, b3);
    // PV: O^T[d][q] += V^T-frag x P-frag
    o0 = mfma32(*(const bf16x8*)&VB[lo5 * 64 + (((0 + hi) ^ sw) * 8)], p0, o0);
    o0 = mfma32(*(const bf16x8*)&VB[lo5 * 64 + (((2 + hi) ^ sw) * 8)], p1, o0);
    o0 = mfma32(*(const bf16x8*)&VB[lo5 * 64 + (((4 + hi) ^ sw) * 8)], p2, o0);
    o0 = mfma32(*(const bf16x8*)&VB[lo5 * 64 + (((6 + hi) ^ sw) * 8)], p3, o0);
    o1 = mfma32(*(const bf16x8*)&VB[(32 + lo5) * 64 + (((0 + hi) ^ sw) * 8)], p0, o1);
    o1 = mfma32(*(const bf16x8*)&VB[(32 + lo5) * 64 + (((2 + hi) ^ sw) * 8)], p1, o1);
    o1 = mfma32(*(const bf16x8*)&VB[(32 + lo5) * 64 + (((4 + hi) ^ sw) * 8)], p2, o1);
    o1 = mfma32(*(const bf16x8*)&VB[(32 + lo5) * 64 + (((6 + hi) ^ sw) * 8)], p3, o1);
  };

  const int nt = 2 * jb + 2;
  stage(0, 0);
  __syncthreads();
  int cur = 0;
  for (int kt = 0; kt < nt; ++kt) {
    if (kt + 1 < nt) stage(cur ^ 1, (kt + 1) * 64);
    if (kt <= dktA) attend(cur, kt, qw0A, dktA, qA, mA, lsA, oA0, oA1);
    if (kt <= dktB) attend(cur, kt, qw0B, dktB, qB, mB, lsB, oB0, oB1);
    __syncthreads();
    cur ^= 1;
  }

  const int b = bh >> 4, h = bh & 15;
  {
    float inv = 1.f / lsA;
    u16* cp = ctx + ((size_t)b * S_ + qw0A + lo5) * D_ + h * 64 + hi * 4;
    #pragma unroll
    for (int rg = 0; rg < 4; ++rg) {
      ushort4 o4;
      o4.x = f2b(oA0[rg * 4 + 0] * inv); o4.y = f2b(oA0[rg * 4 + 1] * inv);
      o4.z = f2b(oA0[rg * 4 + 2] * inv); o4.w = f2b(oA0[rg * 4 + 3] * inv);
      *(ushort4*)(cp + rg * 8) = o4;
      o4.x = f2b(oA1[rg * 4 + 0] * inv); o4.y = f2b(oA1[rg * 4 + 1] * inv);
      o4.z = f2b(oA1[rg * 4 + 2] * inv); o4.w = f2b(oA1[rg * 4 + 3] * inv);
      *(ushort4*)(cp + 32 + rg * 8) = o4;
    }
  }
  {
    float inv = 1.f / lsB;
    u16* cp = ctx + ((size_t)b * S_ + qw0B + lo5) * D_ + h * 64 + hi * 4;
    #pragma unroll
    for (int rg = 0; rg < 4; ++rg) {
      ushort4 o4;
      o4.x = f2b(oB0[rg * 4 + 0] * inv); o4.y = f2b(oB0[rg * 4 + 1] * inv);
      o4.z = f2b(oB0[rg * 4 + 2] * inv); o4.w = f2b(oB0[rg * 4 + 3] * inv);
      *(ushort4*)(cp + rg * 8) = o4;
      o4.x = f2b(oB1[rg * 4 + 0] * inv); o4.y = f2b(oB1[rg * 4 + 1] * inv);
      o4.z = f2b(oB1[rg * 4 + 2] * inv); o4.w = f2b(oB1[rg * 4 + 3] * inv);
      *(ushort4*)(cp + 32 + rg * 8) = o4;
    }
  }
}

extern "C" void kernel_launch(void* const* d_in, const int* in_sizes, int n_in,
                              void* d_out, int out_size, void* d_ws, size_t ws_size,
                              hipStream_t stream) {
  const float* x  = (const float*)d_in[0];
  const float* Wq = (const float*)d_in[1];
  const float* Wk = (const float*)d_in[2];
  const float* Wv = (const float*)d_in[3];
  const float* Wo = (const float*)d_in[4];
  const float* bo = (const float*)d_in[5];
  float* out = (float*)d_out;
  (void)in_sizes; (void)n_in; (void)out_size; (void)ws_size;

  char* p = (char*)d_ws;
  const size_t NTOK = (size_t)B_ * S_;  // 8192
  u16* xb    = (u16*)p; p += NTOK * D_ * 2;
  u16* wqkvt = (u16*)p; p += (size_t)3 * D_ * D_ * 2;
  u16* wot   = (u16*)p; p += (size_t)D_ * D_ * 2;
  u16* Qg    = (u16*)p; p += NTOK * D_ * 2;           // [bh][s][hd]
  u16* Kg    = (u16*)p; p += NTOK * D_ * 2;           // [bh][s][hd]
  u16* Vtg   = (u16*)p; p += NTOK * D_ * 2;           // [bh][hd][s]
  u16* ctx   = (u16*)p; p += NTOK * D_ * 2;           // [b][s][d]

  int n4 = (int)(NTOK * D_ / 4);
  k_cvt<<<dim3((n4 + 255) / 256), dim3(256), 0, stream>>>(x, xb, n4);
  dim3 tb(32, 8), tg(32, 32);
  k_wt<<<tg, tb, 0, stream>>>(Wq, wqkvt);
  k_wt<<<tg, tb, 0, stream>>>(Wk, wqkvt + (size_t)D_ * D_);
  k_wt<<<tg, tb, 0, stream>>>(Wv, wqkvt + (size_t)2 * D_ * D_);
  k_wt<<<tg, tb, 0, stream>>>(Wo, wot);
  k_gemm<0><<<dim3(3 * D_ / 128, NTOK / 128), dim3(256), 0, stream>>>(
      xb, wqkvt, 3 * D_, D_, Qg, Kg, Vtg, nullptr, nullptr);
  k_attn<<<dim3(8, B_ * H_), dim3(256), 0, stream>>>(Qg, Kg, Vtg, ctx);
  k_gemm<1><<<dim3(D_ / 128, NTOK / 128), dim3(256), 0, stream>>>(
      ctx, wot, D_, D_, nullptr, nullptr, nullptr, bo, out);
}

// Round 4
// 210.939 us; speedup vs baseline: 1.9832x; 1.0239x over previous
//
#include <hip/hip_runtime.h>

#define B_ 4
#define S_ 2048
#define D_ 1024
#define H_ 16
#define HD_ 64

typedef __bf16 bf16x8 __attribute__((ext_vector_type(8)));
typedef float f32x4 __attribute__((ext_vector_type(4)));
typedef float f32x16 __attribute__((ext_vector_type(16)));
typedef unsigned short u16;

__device__ __forceinline__ u16 f2b(float f) {
  unsigned u = __builtin_bit_cast(unsigned, f);
  return (u16)((u + 0x7FFFu + ((u >> 16) & 1u)) >> 16);
}

__device__ __forceinline__ void gll16(const void* g, void* l) {
  __builtin_amdgcn_global_load_lds(
      (const __attribute__((address_space(1))) void*)g,
      (__attribute__((address_space(3))) void*)l, 16, 0, 0);
}

__device__ __forceinline__ f32x4 mfma16(bf16x8 a, bf16x8 b, f32x4 c) {
  return __builtin_amdgcn_mfma_f32_16x16x32_bf16(a, b, c, 0, 0, 0);
}
__device__ __forceinline__ f32x16 mfma32(bf16x8 a, bf16x8 b, f32x16 c) {
  return __builtin_amdgcn_mfma_f32_32x32x16_bf16(a, b, c, 0, 0, 0);
}

__device__ __forceinline__ unsigned cvtpk(float lo, float hi) {
  unsigned r;
  asm("v_cvt_pk_bf16_f32 %0, %1, %2" : "=v"(r) : "v"(lo), "v"(hi));
  return r;
}
__device__ __forceinline__ void plswap(unsigned& a, unsigned& b) {
  asm("v_permlane32_swap_b32 %0, %1" : "+v"(a), "+v"(b));
}
__device__ __forceinline__ bf16x8 mk8(unsigned a, unsigned b, unsigned c, unsigned d) {
  union { unsigned u[4]; bf16x8 v; } x;
  x.u[0] = a; x.u[1] = b; x.u[2] = c; x.u[3] = d;
  return x.v;
}

// ---- x: f32 -> bf16, vectorized x4 ----
__global__ __launch_bounds__(256) void k_cvt(const float* __restrict__ in,
                                             u16* __restrict__ out, int n4) {
  int i = blockIdx.x * 256 + threadIdx.x;
  if (i < n4) {
    float4 f = reinterpret_cast<const float4*>(in)[i];
    ushort4 o;
    o.x = f2b(f.x); o.y = f2b(f.y); o.z = f2b(f.z); o.w = f2b(f.w);
    reinterpret_cast<ushort4*>(out)[i] = o;
  }
}

// ---- W[1024][1024] f32 -> Wt[n][k] bf16 (transpose via LDS tile) ----
__global__ __launch_bounds__(256) void k_wt(const float* __restrict__ W,
                                            u16* __restrict__ Wt) {
  __shared__ float tile[32][33];
  int bx = blockIdx.x * 32, by = blockIdx.y * 32;
  int tx = threadIdx.x, ty = threadIdx.y;
  #pragma unroll
  for (int i = ty; i < 32; i += 8)
    tile[i][tx] = W[(size_t)(by + i) * D_ + bx + tx];
  __syncthreads();
  #pragma unroll
  for (int i = ty; i < 32; i += 8)
    Wt[(size_t)(bx + i) * D_ + by + tx] = f2b(tile[tx][i]);
}

// ---- QKV GEMM v2: 256x256 tile, BK=32, 4-slot LDS ring, counted vmcnt ----
// 512 threads = 8 waves (2M x 4N); wave tile 128x64; swizzled LDS (T2);
// depth-2 prefetch with vmcnt(8); single s_barrier per K-tile; setprio (T5);
// XCD-swizzled block id (T1). Scatter epilogue to per-head Q/K/V layouts.
__global__ __launch_bounds__(512, 2) void k_gemm_qkv(
    const u16* __restrict__ A, const u16* __restrict__ Bt,
    u16* __restrict__ q, u16* __restrict__ kk, u16* __restrict__ v) {
  constexpr int K = D_;       // 1024
  constexpr int NT = K / 32;  // 32 K-tiles
  __shared__ __align__(16) u16 As[4][256 * 32];
  __shared__ __align__(16) u16 Bs[4][256 * 32];
  // XCD swizzle: grid 384 = 12 n-tiles x 32 m-tiles, 384 % 8 == 0
  const int cpx = gridDim.x >> 3;
  const int id = blockIdx.x;
  const int swz = (id & 7) * cpx + (id >> 3);
  const int bx = swz % 12, by = swz / 12;
  const int m0 = by * 256, n0 = bx * 256;
  const int t = threadIdx.x, lane = t & 63, w = t >> 6;
  const int wr = w >> 2, wc = w & 3;
  const int lr = lane & 15, lg = lane >> 4;
  const int slot = lg ^ ((lr >> 1) & 3);  // T2 read-side swizzle

  // staging: thread t -> LDS row t>>2, slot t&3 (linear dest);
  // source chunk = (t&3) ^ ((row>>1)&3) pre-applies the swizzle.
  const int srow = t >> 2;
  const int sch = (t & 3) ^ ((t >> 3) & 3);
  const u16* gA = A + (size_t)(m0 + srow) * K + sch * 8;
  const u16* gB = Bt + (size_t)(n0 + srow) * K + sch * 8;

  f32x4 acc[8][4] = {};

  auto stage = [&](int b, int kt) {
    const u16* pa = gA + kt * 32;
    const u16* pb = gB + kt * 32;
    gll16(pa, &As[b][t * 8]);
    gll16(pa + (size_t)128 * K, &As[b][4096 + t * 8]);
    gll16(pb, &Bs[b][t * 8]);
    gll16(pb + (size_t)128 * K, &Bs[b][4096 + t * 8]);
  };

  stage(0, 0);
  stage(1, 1);
  for (int kt = 0; kt < NT; ++kt) {
    const int b = kt & 3;
    if (kt + 2 < NT) {
      stage((kt + 2) & 3, kt + 2);
      asm volatile("s_waitcnt vmcnt(8)" ::: "memory");
    } else if (kt + 1 < NT) {
      asm volatile("s_waitcnt vmcnt(4)" ::: "memory");
    } else {
      asm volatile("s_waitcnt vmcnt(0)" ::: "memory");
    }
    __builtin_amdgcn_sched_barrier(0);
    __builtin_amdgcn_s_barrier();
    __builtin_amdgcn_sched_barrier(0);
    bf16x8 bfr[4], afr[4];
    #pragma unroll
    for (int j = 0; j < 4; ++j)
      bfr[j] = *(const bf16x8*)&Bs[b][(wc * 64 + j * 16 + lr) * 32 + slot * 8];
    #pragma unroll
    for (int i = 0; i < 4; ++i)
      afr[i] = *(const bf16x8*)&As[b][(wr * 128 + i * 16 + lr) * 32 + slot * 8];
    __builtin_amdgcn_s_setprio(1);
    #pragma unroll
    for (int i = 0; i < 4; ++i)
      #pragma unroll
      for (int j = 0; j < 4; ++j)
        acc[i][j] = mfma16(afr[i], bfr[j], acc[i][j]);
    __builtin_amdgcn_s_setprio(0);
    #pragma unroll
    for (int i = 0; i < 4; ++i)
      afr[i] = *(const bf16x8*)&As[b][(wr * 128 + (i + 4) * 16 + lr) * 32 + slot * 8];
    __builtin_amdgcn_s_setprio(1);
    #pragma unroll
    for (int i = 0; i < 4; ++i)
      #pragma unroll
      for (int j = 0; j < 4; ++j)
        acc[i + 4][j] = mfma16(afr[i], bfr[j], acc[i + 4][j]);
    __builtin_amdgcn_s_setprio(0);
    __builtin_amdgcn_sched_barrier(0);
  }
  // epilogue: scatter to per-head layouts (V transposed), scale folded into Q
  #pragma unroll
  for (int i = 0; i < 8; ++i) {
    #pragma unroll
    for (int j = 0; j < 4; ++j) {
      #pragma unroll
      for (int r = 0; r < 4; ++r) {
        int m = m0 + wr * 128 + i * 16 + lg * 4 + r;
        int n = n0 + wc * 64 + j * 16 + lr;
        float val = acc[i][j][r];
        int which = n >> 10, nn = n & 1023;
        int h = nn >> 6, hd = nn & 63;
        int b2 = m >> 11, s = m & 2047;
        size_t bh = (size_t)(b2 * H_ + h);
        if (which == 0)
          q[(bh * S_ + s) * HD_ + hd] = f2b(val * 0.1803368801111f);  // 1/8*log2e
        else if (which == 1)
          kk[(bh * S_ + s) * HD_ + hd] = f2b(val);
        else
          v[(bh * HD_ + hd) * S_ + s] = f2b(val);
      }
    }
  }
}

// ---- output-projection GEMM (m97-style 128x128), f32 out + bias ----
__global__ __launch_bounds__(256) void k_gemm_proj(
    const u16* __restrict__ A, const u16* __restrict__ Bt, int N, int K,
    const float* __restrict__ bias, float* __restrict__ out) {
  constexpr int BK = 32;
  __shared__ __align__(16) u16 As[128 * BK];
  __shared__ __align__(16) u16 Bs[128 * BK];
  const int m0 = blockIdx.y * 128, n0 = blockIdx.x * 128;
  const int t = threadIdx.x, lane = t & 63, w = t >> 6;
  const int wr = w >> 1, wc = w & 1;
  const int lr = lane & 15, lg = lane >> 4;
  f32x4 acc[4][4] = {};
  const int rA = t >> 2, cA = (t & 3) * 8;
  const u16* pa0 = A + (size_t)(m0 + rA) * K + cA;
  const u16* pa1 = pa0 + (size_t)64 * K;
  const u16* pb0 = Bt + (size_t)(n0 + rA) * K + cA;
  const u16* pb1 = pb0 + (size_t)64 * K;
  for (int k0 = 0; k0 < K; k0 += BK) {
    gll16(pa0 + k0, As + t * 8);
    gll16(pa1 + k0, As + 64 * BK + t * 8);
    gll16(pb0 + k0, Bs + t * 8);
    gll16(pb1 + k0, Bs + 64 * BK + t * 8);
    __syncthreads();
    bf16x8 af[4], bf[4];
    #pragma unroll
    for (int i = 0; i < 4; ++i)
      af[i] = *reinterpret_cast<const bf16x8*>(
          &As[(wr * 64 + i * 16 + lr) * BK + lg * 8]);
    #pragma unroll
    for (int j = 0; j < 4; ++j)
      bf[j] = *reinterpret_cast<const bf16x8*>(
          &Bs[(wc * 64 + j * 16 + lr) * BK + lg * 8]);
    #pragma unroll
    for (int i = 0; i < 4; ++i)
      #pragma unroll
      for (int j = 0; j < 4; ++j)
        acc[i][j] = mfma16(af[i], bf[j], acc[i][j]);
    __syncthreads();
  }
  #pragma unroll
  for (int i = 0; i < 4; ++i)
    #pragma unroll
    for (int j = 0; j < 4; ++j)
      #pragma unroll
      for (int r = 0; r < 4; ++r) {
        int m = m0 + wr * 64 + i * 16 + lg * 4 + r;
        int n = n0 + wc * 64 + j * 16 + lr;
        out[(size_t)m * N + n] = acc[i][j][r] + bias[n];
      }
}

// ---- causal flash attention v3: swapped QK^T, 32x32 MFMA, in-reg softmax ----
__global__ __launch_bounds__(256, 2) void k_attn(
    const u16* __restrict__ Qg, const u16* __restrict__ Kg,
    const u16* __restrict__ Vtg, u16* __restrict__ ctx) {
  __shared__ __align__(16) u16 Ks[2][64 * 64];   // [key][hd], chunk-swizzled
  __shared__ __align__(16) u16 Vs[2][64 * 64];   // [hd][key], chunk-swizzled
  const int ja = blockIdx.x, jb = 15 - ja, bh = blockIdx.y;
  const int t = threadIdx.x, l = t & 63, wq = t >> 6;
  const int lo5 = l & 31, hi = l >> 5, sw = l & 7;
  const size_t base = (size_t)bh * S_ * HD_;
  const int srow = t >> 3, sch = (t & 7) ^ (srow & 7);

  const int qw0A = ja * 128 + wq * 32, qw0B = jb * 128 + wq * 32;
  const int dktA = qw0A >> 6, dktB = qw0B >> 6;

  bf16x8 qA[4], qB[4];
  {
    const u16* qp = Qg + base + (size_t)(qw0A + lo5) * HD_ + hi * 8;
    #pragma unroll
    for (int di = 0; di < 4; ++di) qA[di] = *(const bf16x8*)(qp + di * 16);
    qp = Qg + base + (size_t)(qw0B + lo5) * HD_ + hi * 8;
    #pragma unroll
    for (int di = 0; di < 4; ++di) qB[di] = *(const bf16x8*)(qp + di * 16);
  }
  float mA = -1e30f, lsA = 0.f, mB = -1e30f, lsB = 0.f;
  f32x16 oA0 = {}, oA1 = {}, oB0 = {}, oB1 = {};

  auto stage = [&](int buf, int kb) {
    gll16(Kg + base + (size_t)(kb + srow) * HD_ + sch * 8, &Ks[buf][t * 8]);
    gll16(Kg + base + (size_t)(kb + 32 + srow) * HD_ + sch * 8, &Ks[buf][2048 + t * 8]);
    gll16(Vtg + base + (size_t)srow * S_ + kb + sch * 8, &Vs[buf][t * 8]);
    gll16(Vtg + base + (size_t)(32 + srow) * S_ + kb + sch * 8, &Vs[buf][2048 + t * 8]);
  };

  auto attend = [&](int buf, int kt, int qw0, int dkt, const bf16x8 (&qf)[4],
                    float& m_r, float& l_r, f32x16& o0, f32x16& o1) {
    const u16* KB = &Ks[buf][0];
    const u16* VB = &Vs[buf][0];
    f32x16 s0 = {}, s1 = {};
    #pragma unroll
    for (int di = 0; di < 4; ++di)
      s0 = mfma32(*(const bf16x8*)&KB[lo5 * 64 + (((di * 2 + hi) ^ sw) * 8)],
                  qf[di], s0);
    #pragma unroll
    for (int di = 0; di < 4; ++di)
      s1 = mfma32(*(const bf16x8*)&KB[(32 + lo5) * 64 + (((di * 2 + hi) ^ sw) * 8)],
                  qf[di], s1);
    if (kt == dkt) {
      int qrel = qw0 + lo5 - kt * 64;
      #pragma unroll
      for (int r = 0; r < 16; ++r) {
        int k0 = (r & 3) + 8 * (r >> 2) + 4 * hi;
        if (k0 > qrel) s0[r] = -1e30f;
        if (k0 + 32 > qrel) s1[r] = -1e30f;
      }
    }
    float tm = fmaxf(s0[0], s1[0]);
    #pragma unroll
    for (int r = 1; r < 16; ++r) tm = fmaxf(tm, fmaxf(s0[r], s1[r]));
    tm = fmaxf(tm, __shfl_xor(tm, 32));
    float mn = fmaxf(m_r, tm);
    float rescale = __builtin_amdgcn_exp2f(m_r - mn);
    m_r = mn;
    float sum = 0.f;
    #pragma unroll
    for (int r = 0; r < 16; ++r) { s0[r] = __builtin_amdgcn_exp2f(s0[r] - mn); sum += s0[r]; }
    #pragma unroll
    for (int r = 0; r < 16; ++r) { s1[r] = __builtin_amdgcn_exp2f(s1[r] - mn); sum += s1[r]; }
    sum += __shfl_xor(sum, 32);
    l_r = l_r * rescale + sum;
    o0 *= rescale;
    o1 *= rescale;
    unsigned a0 = cvtpk(s0[0], s0[1]), b0 = cvtpk(s0[4], s0[5]); plswap(a0, b0);
    unsigned a1 = cvtpk(s0[2], s0[3]), b1 = cvtpk(s0[6], s0[7]); plswap(a1, b1);
    unsigned a2 = cvtpk(s0[8], s0[9]), b2 = cvtpk(s0[12], s0[13]); plswap(a2, b2);
    unsigned a3 = cvtpk(s0[10], s0[11]), b3 = cvtpk(s0[14], s0[15]); plswap(a3, b3);
    bf16x8 p0 = mk8(a0, a1, b0, b1), p1 = mk8(a2, a3, b2, b3);
    a0 = cvtpk(s1[0], s1[1]); b0 = cvtpk(s1[4], s1[5]); plswap(a0, b0);
    a1 = cvtpk(s1[2], s1[3]); b1 = cvtpk(s1[6], s1[7]); plswap(a1, b1);
    a2 = cvtpk(s1[8], s1[9]); b2 = cvtpk(s1[12], s1[13]); plswap(a2, b2);
    a3 = cvtpk(s1[10], s1[11]); b3 = cvtpk(s1[14], s1[15]); plswap(a3, b3);
    bf16x8 p2 = mk8(a0, a1, b0, b1), p3 = mk8(a2, a3, b2, b3);
    o0 = mfma32(*(const bf16x8*)&VB[lo5 * 64 + (((0 + hi) ^ sw) * 8)], p0, o0);
    o0 = mfma32(*(const bf16x8*)&VB[lo5 * 64 + (((2 + hi) ^ sw) * 8)], p1, o0);
    o0 = mfma32(*(const bf16x8*)&VB[lo5 * 64 + (((4 + hi) ^ sw) * 8)], p2, o0);
    o0 = mfma32(*(const bf16x8*)&VB[lo5 * 64 + (((6 + hi) ^ sw) * 8)], p3, o0);
    o1 = mfma32(*(const bf16x8*)&VB[(32 + lo5) * 64 + (((0 + hi) ^ sw) * 8)], p0, o1);
    o1 = mfma32(*(const bf16x8*)&VB[(32 + lo5) * 64 + (((2 + hi) ^ sw) * 8)], p1, o1);
    o1 = mfma32(*(const bf16x8*)&VB[(32 + lo5) * 64 + (((4 + hi) ^ sw) * 8)], p2, o1);
    o1 = mfma32(*(const bf16x8*)&VB[(32 + lo5) * 64 + (((6 + hi) ^ sw) * 8)], p3, o1);
  };

  const int nt = 2 * jb + 2;
  stage(0, 0);
  __syncthreads();
  int cur = 0;
  for (int kt = 0; kt < nt; ++kt) {
    if (kt + 1 < nt) stage(cur ^ 1, (kt + 1) * 64);
    if (kt <= dktA) attend(cur, kt, qw0A, dktA, qA, mA, lsA, oA0, oA1);
    if (kt <= dktB) attend(cur, kt, qw0B, dktB, qB, mB, lsB, oB0, oB1);
    __syncthreads();
    cur ^= 1;
  }

  const int b = bh >> 4, h = bh & 15;
  {
    float inv = 1.f / lsA;
    u16* cp = ctx + ((size_t)b * S_ + qw0A + lo5) * D_ + h * 64 + hi * 4;
    #pragma unroll
    for (int rg = 0; rg < 4; ++rg) {
      ushort4 o4;
      o4.x = f2b(oA0[rg * 4 + 0] * inv); o4.y = f2b(oA0[rg * 4 + 1] * inv);
      o4.z = f2b(oA0[rg * 4 + 2] * inv); o4.w = f2b(oA0[rg * 4 + 3] * inv);
      *(ushort4*)(cp + rg * 8) = o4;
      o4.x = f2b(oA1[rg * 4 + 0] * inv); o4.y = f2b(oA1[rg * 4 + 1] * inv);
      o4.z = f2b(oA1[rg * 4 + 2] * inv); o4.w = f2b(oA1[rg * 4 + 3] * inv);
      *(ushort4*)(cp + 32 + rg * 8) = o4;
    }
  }
  {
    float inv = 1.f / lsB;
    u16* cp = ctx + ((size_t)b * S_ + qw0B + lo5) * D_ + h * 64 + hi * 4;
    #pragma unroll
    for (int rg = 0; rg < 4; ++rg) {
      ushort4 o4;
      o4.x = f2b(oB0[rg * 4 + 0] * inv); o4.y = f2b(oB0[rg * 4 + 1] * inv);
      o4.z = f2b(oB0[rg * 4 + 2] * inv); o4.w = f2b(oB0[rg * 4 + 3] * inv);
      *(ushort4*)(cp + rg * 8) = o4;
      o4.x = f2b(oB1[rg * 4 + 0] * inv); o4.y = f2b(oB1[rg * 4 + 1] * inv);
      o4.z = f2b(oB1[rg * 4 + 2] * inv); o4.w = f2b(oB1[rg * 4 + 3] * inv);
      *(ushort4*)(cp + 32 + rg * 8) = o4;
    }
  }
}

extern "C" void kernel_launch(void* const* d_in, const int* in_sizes, int n_in,
                              void* d_out, int out_size, void* d_ws, size_t ws_size,
                              hipStream_t stream) {
  const float* x  = (const float*)d_in[0];
  const float* Wq = (const float*)d_in[1];
  const float* Wk = (const float*)d_in[2];
  const float* Wv = (const float*)d_in[3];
  const float* Wo = (const float*)d_in[4];
  const float* bo = (const float*)d_in[5];
  float* out = (float*)d_out;
  (void)in_sizes; (void)n_in; (void)out_size; (void)ws_size;

  char* p = (char*)d_ws;
  const size_t NTOK = (size_t)B_ * S_;  // 8192
  u16* xb    = (u16*)p; p += NTOK * D_ * 2;
  u16* wqkvt = (u16*)p; p += (size_t)3 * D_ * D_ * 2;
  u16* wot   = (u16*)p; p += (size_t)D_ * D_ * 2;
  u16* Qg    = (u16*)p; p += NTOK * D_ * 2;           // [bh][s][hd]
  u16* Kg    = (u16*)p; p += NTOK * D_ * 2;           // [bh][s][hd]
  u16* Vtg   = (u16*)p; p += NTOK * D_ * 2;           // [bh][hd][s]
  u16* ctx   = (u16*)p; p += NTOK * D_ * 2;           // [b][s][d]

  int n4 = (int)(NTOK * D_ / 4);
  k_cvt<<<dim3((n4 + 255) / 256), dim3(256), 0, stream>>>(x, xb, n4);
  dim3 tb(32, 8), tg(32, 32);
  k_wt<<<tg, tb, 0, stream>>>(Wq, wqkvt);
  k_wt<<<tg, tb, 0, stream>>>(Wk, wqkvt + (size_t)D_ * D_);
  k_wt<<<tg, tb, 0, stream>>>(Wv, wqkvt + (size_t)2 * D_ * D_);
  k_wt<<<tg, tb, 0, stream>>>(Wo, wot);
  // QKV: grid 12 n-tiles x 32 m-tiles = 384 blocks (1-D, XCD-swizzled inside)
  k_gemm_qkv<<<dim3(384), dim3(512), 0, stream>>>(xb, wqkvt, Qg, Kg, Vtg);
  k_attn<<<dim3(8, B_ * H_), dim3(256), 0, stream>>>(Qg, Kg, Vtg, ctx);
  k_gemm_proj<<<dim3(D_ / 128, NTOK / 128), dim3(256), 0, stream>>>(
      ctx, wot, D_, D_, bo, out);
}